// Round 4
// baseline (488.156 us; speedup 1.0000x reference)
//
#include <hip/hip_runtime.h>
#include <hip/hip_bf16.h>
#include <stdint.h>

// Problem constants
#define N_NODES 8192
#define F_IN    768
#define F_OUT   128

typedef _Float16 f16_t;
typedef _Float16 f16x8 __attribute__((ext_vector_type(8)));
typedef _Float16 f16x4 __attribute__((ext_vector_type(4)));
typedef float  f32x4  __attribute__((ext_vector_type(4)));
typedef unsigned short u16x4 __attribute__((ext_vector_type(4)));

static __device__ __forceinline__ unsigned short f16_bits(float x) {
  f16_t h = (f16_t)x;   // RTNE
  return __builtin_bit_cast(unsigned short, h);
}

static __device__ __forceinline__ void gload_lds16(const void* g, void* l) {
  __builtin_amdgcn_global_load_lds(
      (const __attribute__((address_space(1))) unsigned int*)g,
      (__attribute__((address_space(3))) unsigned int*)l, 16, 0, 0);
}

// ---------------------------------------------------------------------------
// prep: blocks 0..95 -> WT[col][k] = f16(W[k][col]);
//       blocks 96..287 -> wxs/wxd[k] = sum_c W[k][c]*a[c] / a[128+c]
// ---------------------------------------------------------------------------
__global__ __launch_bounds__(256) void prep(const float* __restrict__ W,
                                            const float* __restrict__ a,
                                            f16_t* __restrict__ WT,
                                            float* __restrict__ wxs,
                                            float* __restrict__ wxd) {
  if (blockIdx.x < 96) {
    int gid = blockIdx.x * 256 + threadIdx.x;   // 24576 total
    int col = gid / 192;
    int kq  = gid % 192;
    int k0  = kq * 4;
    u16x4 u;
#pragma unroll
    for (int i = 0; i < 4; ++i)
      u[i] = f16_bits(W[(k0 + i) * F_OUT + col]);
    *(u16x4*)(WT + col * F_IN + k0) = u;
  } else {
    const int wave = threadIdx.x >> 6;
    const int lane = threadIdx.x & 63;
    const int row  = (blockIdx.x - 96) * 4 + wave;   // 0..767
    float w0 = W[row * F_OUT + lane];
    float w1 = W[row * F_OUT + 64 + lane];
    float s = w0 * a[lane]       + w1 * a[64 + lane];
    float d = w0 * a[128 + lane] + w1 * a[192 + lane];
#pragma unroll
    for (int m = 1; m <= 32; m <<= 1) {
      s += __shfl_xor(s, m);
      d += __shfl_xor(d, m);
    }
    if (lane == 0) { wxs[row] = s; wxd[row] = d; }
  }
}

// ---------------------------------------------------------------------------
// hp_kernel: Hp = H@W (f16 MFMA), written DIRECTLY in MFMA-B-fragment order:
//   fragment (j32, nt) = 512 f16 at ((j32*8+nt)*512); element (laneB, e)
//   holds Hp[j32*32 + (laneB>>4)*8 + e][nt*16 + (laneB&15)].
// src/dst = H @ wxs/wxd fused into the fp32 H loads (exact fp32).
// BM=16 rows/block, grid 512 x 256.
// ---------------------------------------------------------------------------
__global__ __launch_bounds__(256, 2) void hp_kernel(
    const float* __restrict__ H, const f16_t* __restrict__ WT,
    const float* __restrict__ wxs, const float* __restrict__ wxd,
    f16_t* __restrict__ HpP, float* __restrict__ srcv, float* __restrict__ dstv)
{
  __shared__ unsigned short h_s[16 * 64];   // f16 H tile, swizzled
  __shared__ float ws_s[F_IN];
  __shared__ float wd_s[F_IN];

  const int tid  = threadIdx.x;
  const int wave = tid >> 6;
  const int lane = tid & 63;
  const int l15  = lane & 15;
  const int g    = lane >> 4;
  const int row0 = blockIdx.x * 16;
  const int lrow = tid >> 4;   // 0..15
  const int q    = tid & 15;

  for (int i = tid; i < F_IN; i += 256) { ws_s[i] = wxs[i]; wd_s[i] = wxd[i]; }

  f32x4 zero4 = {0.f, 0.f, 0.f, 0.f};
  f32x4 acc[2];
  acc[0] = zero4; acc[1] = zero4;
  float ps0 = 0.f, pd0 = 0.f;

  __syncthreads();

  for (int c = 0; c < F_IN / 64; ++c) {
    const int k0 = c * 64;
    f32x4 h0 = *(const f32x4*)&H[(size_t)(row0 + lrow) * F_IN + k0 + q * 4];
    f32x4 as = *(const f32x4*)&ws_s[k0 + q * 4];
    f32x4 ad = *(const f32x4*)&wd_s[k0 + q * 4];
#pragma unroll
    for (int e = 0; e < 4; ++e) {
      ps0 += h0[e] * as[e]; pd0 += h0[e] * ad[e];
    }
    u16x4 u0;
#pragma unroll
    for (int e = 0; e < 4; ++e) u0[e] = f16_bits(h0[e]);
    const int g8 = q >> 1, hh = (q & 1) * 4;
    *(u16x4*)&h_s[lrow * 64 + ((g8 ^ (lrow & 7)) * 8) + hh] = u0;
    __syncthreads();

#pragma unroll
    for (int s = 0; s < 2; ++s) {
      f16x8 af = *(const f16x8*)&h_s[l15 * 64 + (((s * 4 + g) ^ (l15 & 7)) * 8)];
#pragma unroll
      for (int ntl = 0; ntl < 2; ++ntl) {
        const int nt = wave * 2 + ntl;
        f16x8 bfv = *(const f16x8*)&WT[(size_t)(nt * 16 + l15) * F_IN + k0 + s * 32 + g * 8];
        acc[ntl] = __builtin_amdgcn_mfma_f32_16x16x32_f16(af, bfv, acc[ntl], 0, 0, 0);
      }
    }
    __syncthreads();
  }

  // exact fp32 src/dst: reduce over the 16 lanes sharing a row
#pragma unroll
  for (int m = 1; m <= 8; m <<= 1) {
    ps0 += __shfl_xor(ps0, m);
    pd0 += __shfl_xor(pd0, m);
  }
  if (q == 0) { srcv[row0 + lrow] = ps0; dstv[row0 + lrow] = pd0; }

  // Direct fragment-order store (coalesced).
  // D layout: acc[ntl][r] = Hp[row0 + g*4 + r][(wave*2+ntl)*16 + l15]
  const int j32 = blockIdx.x >> 1;
  const int mt  = blockIdx.x & 1;
#pragma unroll
  for (int ntl = 0; ntl < 2; ++ntl) {
    const int ntB = wave * 2 + ntl;
    const int gB  = mt * 2 + (g >> 1);
    f16x4 v;
#pragma unroll
    for (int r = 0; r < 4; ++r) v[r] = (f16_t)acc[ntl][r];
    const size_t elem = ((size_t)(j32 * 8 + ntB)) * 512 + (gB * 16 + l15) * 8 + (g & 1) * 4;
    *(f16x4*)(HpP + elem) = v;
  }
}

// ---------------------------------------------------------------------------
// attn_kernel: out[i] = (sum_j w_ij * Hp[j]) / (sum_j w_ij)
//   w_ij = exp(lrelu(masked s_ij) - M_i), M_i = max(0, src_i + max_j dst_j)
// BM=16 rows/block, grid 512 x 512 thr (8 waves = 8 j-stripes of 32).
// Counted-vmcnt pipeline (T3/T4): stage 2 tiles ahead via global_load_lds,
// raw s_barrier (NO vmcnt drain) + asm s_waitcnt vmcnt(2). Two barriers/iter.
// dst read from global (L1-resident 32KB, lane-uniform broadcast) -> LDS
// ~33KB -> 4 blocks/CU (32 waves/CU).
// ---------------------------------------------------------------------------
__global__ __launch_bounds__(512, 8) void attn_kernel(
    const float* __restrict__ adj, const f16_t* __restrict__ HpP,
    const float* __restrict__ srcv, const float* __restrict__ dstv,
    float* __restrict__ out)
{
  __shared__ __align__(16) float adj_s[2][4096];      // 2 x 16KB
  __shared__ float zred[8][16];
  __shared__ float mred[8];

  const int tid  = threadIdx.x;
  const int wave = tid >> 6;
  const int lane = tid & 63;
  const int l15  = lane & 15;
  const int g    = lane >> 4;
  const int row0 = blockIdx.x * 16;

#define STAGE(buf, tt)                                                         \
  do {                                                                         \
    _Pragma("unroll")                                                          \
    for (int rr = 0; rr < 2; ++rr) {                                           \
      const int r = wave * 2 + rr;                                             \
      const float* gp = adj + (size_t)(row0 + r) * N_NODES + (tt) * 256 +      \
                        ((lane ^ (r & 7)) << 2);                               \
      gload_lds16(gp, &adj_s[buf][r * 256]);                                   \
    }                                                                          \
  } while (0)

  // stage tiles 0 and 1 (2-deep pipeline)
  STAGE(0, 0);
  STAGE(1, 1);

  // global max(dst) (no LDS staging of dst)
  float mloc = -3.0e38f;
  for (int i = tid; i < N_NODES / 4; i += 512) {
    f32x4 v = ((const f32x4*)dstv)[i];
    mloc = fmaxf(mloc, fmaxf(fmaxf(v[0], v[1]), fmaxf(v[2], v[3])));
  }
#pragma unroll
  for (int m = 1; m <= 32; m <<= 1) mloc = fmaxf(mloc, __shfl_xor(mloc, m));
  if (lane == 0) mred[wave] = mloc;

  const float my_src = srcv[row0 + l15];
  __syncthreads();   // mred ready (drains prologue stages - once, acceptable)

  float maxdst = mred[0];
#pragma unroll
  for (int w2 = 1; w2 < 8; ++w2) maxdst = fmaxf(maxdst, mred[w2]);
  const float Mi    = fmaxf(0.f, my_src + maxdst);
  const float wmask = __expf(-Mi);        // masked entries: exp(0 - Mi)

  // precomputed swizzled LDS read offsets (constant per thread)
  const int swz  = l15 & 7;
  const int uA   = wave * 8 + g * 2;
  const int offA = l15 * 256 + ((uA ^ swz) << 2);
  const int offB = l15 * 256 + (((uA + 1) ^ swz) << 2);
  const int dstoff = wave * 32 + g * 8;

  f32x4 zero4 = {0.f, 0.f, 0.f, 0.f};
  f32x4 acc[8];
#pragma unroll
  for (int nt = 0; nt < 8; ++nt) acc[nt] = zero4;
  float z_acc = 0.f;

  for (int t = 0; t < 32; ++t) {
    const int cur = t & 1;
    // tile t was staged 2 iterations ago; newest 2 loads are tile t+1's.
    if (t < 31) { asm volatile("s_waitcnt vmcnt(2)" ::: "memory"); }
    else        { asm volatile("s_waitcnt vmcnt(0)" ::: "memory"); }
    __builtin_amdgcn_s_barrier();          // raw: no implicit drain
    __builtin_amdgcn_sched_barrier(0);

    // Hp fragment loads: 8 x 1KB contiguous (L2)
    const f16_t* hb = HpP + ((size_t)(t * 8 + wave) * 8) * 512 + lane * 8;
    f16x8 bf[8];
#pragma unroll
    for (int nt = 0; nt < 8; ++nt) bf[nt] = *(const f16x8*)(hb + nt * 512);

    const float* ab = &adj_s[cur][0];
    f32x4 a0 = *(const f32x4*)(ab + offA);
    f32x4 a1 = *(const f32x4*)(ab + offB);
    f32x4 d0 = *(const f32x4*)&dstv[t * 256 + dstoff];       // broadcast, L1
    f32x4 d1 = *(const f32x4*)&dstv[t * 256 + dstoff + 4];

    f16x8 afr;
#pragma unroll
    for (int e = 0; e < 4; ++e) {
      float s  = my_src + d0[e];
      float lr = fmaxf(s, 0.2f * s);
      float w  = (a0[e] != 0.f) ? __expf(lr - Mi) : wmask;
      f16_t wq = (f16_t)w;
      z_acc += (float)wq;                 // Z from the SAME rounded w
      afr[e] = wq;
    }
#pragma unroll
    for (int e = 0; e < 4; ++e) {
      float s  = my_src + d1[e];
      float lr = fmaxf(s, 0.2f * s);
      float w  = (a1[e] != 0.f) ? __expf(lr - Mi) : wmask;
      f16_t wq = (f16_t)w;
      z_acc += (float)wq;
      afr[4 + e] = wq;
    }

#pragma unroll
    for (int nt = 0; nt < 8; ++nt)
      acc[nt] = __builtin_amdgcn_mfma_f32_16x16x32_f16(afr, bf[nt], acc[nt], 0, 0, 0);

    __builtin_amdgcn_sched_barrier(0);
    __builtin_amdgcn_s_barrier();          // all waves done reading adj_s[cur]
    __builtin_amdgcn_sched_barrier(0);
    if (t < 30) STAGE(cur, t + 2);         // overwrite cur for tile t+2
  }

  // Z: reduce across g-groups (rows = l15)
  float zc = z_acc + __shfl_xor(z_acc, 16);
  zc += __shfl_xor(zc, 32);
  if (lane < 16) zred[wave][lane] = zc;
  __syncthreads();

  // combine 8 stripe-partials in two passes through 32KB LDS (reuse adj_s)
  float* part = &adj_s[0][0];
  if (wave < 4) {
#pragma unroll
    for (int nt = 0; nt < 8; ++nt)
#pragma unroll
      for (int r = 0; r < 4; ++r)
        part[wave * 2048 + (g * 4 + r) * 128 + nt * 16 + l15] = acc[nt][r];
  }
  __syncthreads();
  if (wave >= 4) {
#pragma unroll
    for (int nt = 0; nt < 8; ++nt)
#pragma unroll
      for (int r = 0; r < 4; ++r)
        part[(wave - 4) * 2048 + (g * 4 + r) * 128 + nt * 16 + l15] += acc[nt][r];
  }
  __syncthreads();
  {
    const int orow = tid >> 5;          // 0..15
    const int c0   = (tid & 31) * 4;
    f32x4 s = zero4;
#pragma unroll
    for (int b = 0; b < 4; ++b)
      s += *(const f32x4*)&part[b * 2048 + orow * 128 + c0];
    float zt = 0.f;
#pragma unroll
    for (int w2 = 0; w2 < 8; ++w2) zt += zred[w2][orow];
    *(f32x4*)&out[(size_t)(row0 + orow) * F_OUT + c0] = s * (1.0f / zt);
  }
#undef STAGE
}

// ---------------------------------------------------------------------------
// launch
// ---------------------------------------------------------------------------
extern "C" void kernel_launch(void* const* d_in, const int* in_sizes, int n_in,
                              void* d_out, int out_size, void* d_ws, size_t ws_size,
                              hipStream_t stream) {
  const float* H   = (const float*)d_in[0];   // [8192][768]
  const float* adj = (const float*)d_in[1];   // [8192][8192]
  const float* W   = (const float*)d_in[2];   // [768][128]
  const float* a   = (const float*)d_in[3];   // [256]
  float* out = (float*)d_out;                 // [8192][128]

  // workspace layout (~2.3 MB)
  char* ws = (char*)d_ws;
  f16_t* HpP  = (f16_t*)(ws);                  // 8192*128*2 = 2097152 (fragment-packed)
  f16_t* WT   = (f16_t*)(ws + 2097152);        // 128*768*2  = 196608
  float* wxs  = (float*)(ws + 2293760);        // 768*4
  float* wxd  = (float*)(ws + 2296832);        // 768*4
  float* srcv = (float*)(ws + 2299904);        // 8192*4
  float* dstv = (float*)(ws + 2332672);        // 8192*4

  prep      <<<dim3(288), dim3(256), 0, stream>>>(W, a, WT, wxs, wxd);
  hp_kernel <<<dim3(512), dim3(256), 0, stream>>>(H, WT, wxs, wxd, HpP, srcv, dstv);
  attn_kernel<<<dim3(512), dim3(512), 0, stream>>>(adj, HpP, srcv, dstv, out);
}

// Round 5
// 411.077 us; speedup vs baseline: 1.1875x; 1.1875x over previous
//
#include <hip/hip_runtime.h>
#include <hip/hip_bf16.h>
#include <stdint.h>

// Problem constants
#define N_NODES 8192
#define F_IN    768
#define F_OUT   128

typedef _Float16 f16_t;
typedef _Float16 f16x8 __attribute__((ext_vector_type(8)));
typedef _Float16 f16x4 __attribute__((ext_vector_type(4)));
typedef float  f32x4  __attribute__((ext_vector_type(4)));
typedef unsigned short u16x4 __attribute__((ext_vector_type(4)));

static __device__ __forceinline__ unsigned short f16_bits(float x) {
  f16_t h = (f16_t)x;   // RTNE
  return __builtin_bit_cast(unsigned short, h);
}

static __device__ __forceinline__ void gload_lds16(const void* g, void* l) {
  __builtin_amdgcn_global_load_lds(
      (const __attribute__((address_space(1))) unsigned int*)g,
      (__attribute__((address_space(3))) unsigned int*)l, 16, 0, 0);
}

// ---------------------------------------------------------------------------
// prep: blocks 0..95 -> WT[col][k] = f16(W[k][col]);
//       blocks 96..287 -> wxs/wxd[k] = sum_c W[k][c]*a[c] / a[128+c]
// ---------------------------------------------------------------------------
__global__ __launch_bounds__(256) void prep(const float* __restrict__ W,
                                            const float* __restrict__ a,
                                            f16_t* __restrict__ WT,
                                            float* __restrict__ wxs,
                                            float* __restrict__ wxd) {
  if (blockIdx.x < 96) {
    int gid = blockIdx.x * 256 + threadIdx.x;   // 24576 total
    int col = gid / 192;
    int kq  = gid % 192;
    int k0  = kq * 4;
    u16x4 u;
#pragma unroll
    for (int i = 0; i < 4; ++i)
      u[i] = f16_bits(W[(k0 + i) * F_OUT + col]);
    *(u16x4*)(WT + col * F_IN + k0) = u;
  } else {
    const int wave = threadIdx.x >> 6;
    const int lane = threadIdx.x & 63;
    const int row  = (blockIdx.x - 96) * 4 + wave;   // 0..767
    float w0 = W[row * F_OUT + lane];
    float w1 = W[row * F_OUT + 64 + lane];
    float s = w0 * a[lane]       + w1 * a[64 + lane];
    float d = w0 * a[128 + lane] + w1 * a[192 + lane];
#pragma unroll
    for (int m = 1; m <= 32; m <<= 1) {
      s += __shfl_xor(s, m);
      d += __shfl_xor(d, m);
    }
    if (lane == 0) { wxs[row] = s; wxd[row] = d; }
  }
}

// ---------------------------------------------------------------------------
// hp_kernel (round-3 structure): Hp = H@W (f16 MFMA), written DIRECTLY in
// MFMA-B-fragment order: fragment (j32, nt) = 512 f16 at ((j32*8+nt)*512);
// element (laneB, e) holds Hp[j32*32 + (laneB>>4)*8 + e][nt*16 + (laneB&15)].
// src/dst = H @ wxs/wxd fused into the fp32 H loads (exact fp32).
// BM=32 rows/block, grid 256 x 256.
// ---------------------------------------------------------------------------
__global__ __launch_bounds__(256, 2) void hp_kernel(
    const float* __restrict__ H, const f16_t* __restrict__ WT,
    const float* __restrict__ wxs, const float* __restrict__ wxd,
    f16_t* __restrict__ HpP, float* __restrict__ srcv, float* __restrict__ dstv)
{
  __shared__ unsigned short h_s[32 * 64];   // f16 H tile, swizzled
  __shared__ float ws_s[F_IN];
  __shared__ float wd_s[F_IN];

  const int tid  = threadIdx.x;
  const int wave = tid >> 6;
  const int lane = tid & 63;
  const int l15  = lane & 15;
  const int g    = lane >> 4;
  const int row0 = blockIdx.x * 32;
  const int lrow = tid >> 4;   // 0..15
  const int q    = tid & 15;

  for (int i = tid; i < F_IN; i += 256) { ws_s[i] = wxs[i]; wd_s[i] = wxd[i]; }

  f32x4 zero4 = {0.f, 0.f, 0.f, 0.f};
  f32x4 acc[2][2];
#pragma unroll
  for (int i = 0; i < 2; ++i)
#pragma unroll
    for (int j = 0; j < 2; ++j) acc[i][j] = zero4;
  float ps0 = 0.f, ps1 = 0.f, pd0 = 0.f, pd1 = 0.f;

  __syncthreads();

  for (int c = 0; c < F_IN / 64; ++c) {
    const int k0 = c * 64;
    f32x4 h0 = *(const f32x4*)&H[(size_t)(row0 + lrow) * F_IN + k0 + q * 4];
    f32x4 h1 = *(const f32x4*)&H[(size_t)(row0 + 16 + lrow) * F_IN + k0 + q * 4];
    f32x4 as = *(const f32x4*)&ws_s[k0 + q * 4];
    f32x4 ad = *(const f32x4*)&wd_s[k0 + q * 4];
#pragma unroll
    for (int e = 0; e < 4; ++e) {
      ps0 += h0[e] * as[e]; pd0 += h0[e] * ad[e];
      ps1 += h1[e] * as[e]; pd1 += h1[e] * ad[e];
    }
    u16x4 u0, u1;
#pragma unroll
    for (int e = 0; e < 4; ++e) { u0[e] = f16_bits(h0[e]); u1[e] = f16_bits(h1[e]); }
    const int g8 = q >> 1, hh = (q & 1) * 4;
    *(u16x4*)&h_s[lrow * 64 + ((g8 ^ (lrow & 7)) * 8) + hh] = u0;
    const int r1 = lrow + 16;
    *(u16x4*)&h_s[r1 * 64 + ((g8 ^ (r1 & 7)) * 8) + hh] = u1;
    __syncthreads();

#pragma unroll
    for (int mt = 0; mt < 2; ++mt) {
      const int arow = mt * 16 + l15;
#pragma unroll
      for (int s = 0; s < 2; ++s) {
        f16x8 af = *(const f16x8*)&h_s[arow * 64 + (((s * 4 + g) ^ (arow & 7)) * 8)];
#pragma unroll
        for (int ntl = 0; ntl < 2; ++ntl) {
          const int nt = wave * 2 + ntl;
          f16x8 bfv = *(const f16x8*)&WT[(size_t)(nt * 16 + l15) * F_IN + k0 + s * 32 + g * 8];
          acc[mt][ntl] = __builtin_amdgcn_mfma_f32_16x16x32_f16(af, bfv, acc[mt][ntl], 0, 0, 0);
        }
      }
    }
    __syncthreads();
  }

  // exact fp32 src/dst: reduce over the 16 lanes sharing a row
#pragma unroll
  for (int m = 1; m <= 8; m <<= 1) {
    ps0 += __shfl_xor(ps0, m); ps1 += __shfl_xor(ps1, m);
    pd0 += __shfl_xor(pd0, m); pd1 += __shfl_xor(pd1, m);
  }
  if (q == 0) {
    srcv[row0 + lrow] = ps0; srcv[row0 + 16 + lrow] = ps1;
    dstv[row0 + lrow] = pd0; dstv[row0 + 16 + lrow] = pd1;
  }

  // Direct fragment-order store (coalesced).
  const int j32 = row0 >> 5;
#pragma unroll
  for (int mt = 0; mt < 2; ++mt)
#pragma unroll
    for (int ntl = 0; ntl < 2; ++ntl) {
      const int ntB = wave * 2 + ntl;
      const int gB  = mt * 2 + (g >> 1);
      f16x4 v;
#pragma unroll
      for (int r = 0; r < 4; ++r) v[r] = (f16_t)acc[mt][ntl][r];
      const size_t elem = ((size_t)(j32 * 8 + ntB)) * 512 + (gB * 16 + l15) * 8 + (g & 1) * 4;
      *(f16x4*)(HpP + elem) = v;
    }
}

// ---------------------------------------------------------------------------
// attn_kernel: out[i] = (sum_j w_ij * Hp[j]) / (sum_j w_ij)
//   w_ij = exp(lrelu(masked s_ij) - M_i), M_i = max(0, src_i + max_j dst_j)
// Wave-autonomous: 1024 thr (16 waves), MR=32 rows/block, grid 256 (1/CU).
// Each wave owns j-chunk (16 tiles x 32 j), stages its own 32x32 adj tile
// into a PRIVATE 8KB LDS double-buffer (global_load_lds, pre-swizzled src).
// NO barriers in the main loop. Both 16-row A-tiles share B fragments
// (2x Hp L2-reuse). stage(t+2) issued after the last MFMA-consume so
// in-order vmcnt retire always drains iteration-old stages (no stall).
// ---------------------------------------------------------------------------
__global__ __launch_bounds__(1024, 4) void attn_kernel(
    const float* __restrict__ adj, const f16_t* __restrict__ HpP,
    const float* __restrict__ srcv, const float* __restrict__ dstv,
    float* __restrict__ out)
{
  __shared__ __align__(16) float adj_s[16][2][1024];  // 128KB: per-wave dbuf
  __shared__ float zred[16][32];                      // 2KB
  __shared__ float mred[16];

  const int tid  = threadIdx.x;
  const int wave = tid >> 6;
  const int lane = tid & 63;
  const int l15  = lane & 15;
  const int g    = lane >> 4;
  const int row0 = blockIdx.x * 32;

  // --- stage: 4 x global_load_lds (1KB each), source pre-swizzled so that
  //     LDS slot (r, c') holds content chunk cc = c' ^ (r&7).
#define STAGE(buf, tt)                                                         \
  do {                                                                         \
    const size_t jb_ = (size_t)((tt) * 16 + wave) * 32;                        \
    _Pragma("unroll")                                                          \
    for (int i_ = 0; i_ < 4; ++i_) {                                           \
      const int r_  = i_ * 8 + (lane >> 3);                                    \
      const int cc_ = (lane & 7) ^ (r_ & 7);                                   \
      const float* gp_ = adj + (size_t)(row0 + r_) * N_NODES + jb_ + cc_ * 4;  \
      gload_lds16(gp_, &adj_s[wave][buf][i_ * 256]);                           \
    }                                                                          \
  } while (0)

  STAGE(0, 0);
  STAGE(1, 1);

  // cooperative max(dst): each wave scans 512 floats
  {
    const f32x4* d4 = (const f32x4*)dstv;
    f32x4 v0 = d4[wave * 128 + lane];
    f32x4 v1 = d4[wave * 128 + 64 + lane];
    float mloc = fmaxf(fmaxf(fmaxf(v0[0], v0[1]), fmaxf(v0[2], v0[3])),
                       fmaxf(fmaxf(v1[0], v1[1]), fmaxf(v1[2], v1[3])));
#pragma unroll
    for (int m = 1; m <= 32; m <<= 1) mloc = fmaxf(mloc, __shfl_xor(mloc, m));
    if (lane == 0) mred[wave] = mloc;
  }
  const float my_src0 = srcv[row0 + l15];
  const float my_src1 = srcv[row0 + 16 + l15];
  __syncthreads();   // mred ready (drains prologue stages once - acceptable)

  float maxdst = mred[0];
#pragma unroll
  for (int w2 = 1; w2 < 16; ++w2) maxdst = fmaxf(maxdst, mred[w2]);
  const float Mi0 = fmaxf(0.f, my_src0 + maxdst);
  const float Mi1 = fmaxf(0.f, my_src1 + maxdst);
  const float wm0 = __expf(-Mi0);
  const float wm1 = __expf(-Mi1);

  f32x4 zero4 = {0.f, 0.f, 0.f, 0.f};
  f32x4 acc[2][8];
#pragma unroll
  for (int m = 0; m < 2; ++m)
#pragma unroll
    for (int nt = 0; nt < 8; ++nt) acc[m][nt] = zero4;
  float z0 = 0.f, z1 = 0.f;

  const int rr0 = l15, rr1 = 16 + l15;
  const int offA0 = rr0 * 32 + (((g * 2)     ^ (rr0 & 7)) * 4);
  const int offA1 = rr0 * 32 + (((g * 2 + 1) ^ (rr0 & 7)) * 4);
  const int offB0 = rr1 * 32 + (((g * 2)     ^ (rr1 & 7)) * 4);
  const int offB1 = rr1 * 32 + (((g * 2 + 1) ^ (rr1 & 7)) * 4);

  for (int t = 0; t < 16; ++t) {
    const int buf = t & 1;
    // tile t guaranteed landed (stage(t) older than iter t-1's consumed bf);
    // explicit guard: only stage(t+1)'s 4 loads may remain outstanding.
    asm volatile("s_waitcnt vmcnt(4)" ::: "memory");
    __builtin_amdgcn_sched_barrier(0);

    const float* ab = &adj_s[wave][buf][0];
    f32x4 a00 = *(const f32x4*)&ab[offA0];
    f32x4 a01 = *(const f32x4*)&ab[offA1];
    f32x4 a10 = *(const f32x4*)&ab[offB0];
    f32x4 a11 = *(const f32x4*)&ab[offB1];
    asm volatile("s_waitcnt lgkmcnt(0)" ::: "memory");
    __builtin_amdgcn_sched_barrier(0);

    const size_t j0 = (size_t)(t * 16 + wave) * 32;
    f32x4 d0 = *(const f32x4*)&dstv[j0 + g * 8];
    f32x4 d1 = *(const f32x4*)&dstv[j0 + g * 8 + 4];

    const f16_t* hb = HpP + ((size_t)(t * 16 + wave) * 8) * 512 + lane * 8;
    f16x8 bf0[4];
#pragma unroll
    for (int nt = 0; nt < 4; ++nt) bf0[nt] = *(const f16x8*)(hb + nt * 512);

    // weights for both row-tiles
    f16x8 afr0, afr1;
#pragma unroll
    for (int e = 0; e < 4; ++e) {
      float dd = d0[e];
      float s0 = my_src0 + dd, s1 = my_src1 + dd;
      float w0 = (a00[e] != 0.f) ? __expf(fmaxf(s0, 0.2f * s0) - Mi0) : wm0;
      float w1 = (a10[e] != 0.f) ? __expf(fmaxf(s1, 0.2f * s1) - Mi1) : wm1;
      f16_t q0 = (f16_t)w0, q1 = (f16_t)w1;
      z0 += (float)q0; z1 += (float)q1;
      afr0[e] = q0; afr1[e] = q1;
    }
#pragma unroll
    for (int e = 0; e < 4; ++e) {
      float dd = d1[e];
      float s0 = my_src0 + dd, s1 = my_src1 + dd;
      float w0 = (a01[e] != 0.f) ? __expf(fmaxf(s0, 0.2f * s0) - Mi0) : wm0;
      float w1 = (a11[e] != 0.f) ? __expf(fmaxf(s1, 0.2f * s1) - Mi1) : wm1;
      f16_t q0 = (f16_t)w0, q1 = (f16_t)w1;
      z0 += (float)q0; z1 += (float)q1;
      afr0[4 + e] = q0; afr1[4 + e] = q1;
    }

#pragma unroll
    for (int nt = 0; nt < 4; ++nt) {
      acc[0][nt] = __builtin_amdgcn_mfma_f32_16x16x32_f16(afr0, bf0[nt], acc[0][nt], 0, 0, 0);
      acc[1][nt] = __builtin_amdgcn_mfma_f32_16x16x32_f16(afr1, bf0[nt], acc[1][nt], 0, 0, 0);
    }

    f16x8 bf1[4];
#pragma unroll
    for (int nt = 0; nt < 4; ++nt) bf1[nt] = *(const f16x8*)(hb + (4 + nt) * 512);
#pragma unroll
    for (int nt = 0; nt < 4; ++nt) {
      acc[0][4 + nt] = __builtin_amdgcn_mfma_f32_16x16x32_f16(afr0, bf1[nt], acc[0][4 + nt], 0, 0, 0);
      acc[1][4 + nt] = __builtin_amdgcn_mfma_f32_16x16x32_f16(afr1, bf1[nt], acc[1][4 + nt], 0, 0, 0);
    }

    // stage t+2 LAST: never force-drained until iter t+1's consumes
    __builtin_amdgcn_sched_barrier(0);
    if (t < 14) STAGE(buf, t + 2);
    __builtin_amdgcn_sched_barrier(0);
  }
#undef STAGE

  // Z reduce across g-groups
  z0 += __shfl_xor(z0, 16); z0 += __shfl_xor(z0, 32);
  z1 += __shfl_xor(z1, 16); z1 += __shfl_xor(z1, 32);
  if (lane < 16) { zred[wave][l15] = z0; zred[wave][16 + l15] = z1; }
  __syncthreads();

  // combine 16 j-partials: two passes through the 128KB adj LDS (8 bufs)
  float* part = &adj_s[0][0][0];
  {
    const int b = wave & 7;
    if (wave < 8) {
#pragma unroll
      for (int m = 0; m < 2; ++m)
#pragma unroll
        for (int nt = 0; nt < 8; ++nt)
#pragma unroll
          for (int r = 0; r < 4; ++r)
            part[b * 4096 + (m * 16 + g * 4 + r) * 128 + nt * 16 + l15] = acc[m][nt][r];
    }
    __syncthreads();
    if (wave >= 8) {
#pragma unroll
      for (int m = 0; m < 2; ++m)
#pragma unroll
        for (int nt = 0; nt < 8; ++nt)
#pragma unroll
          for (int r = 0; r < 4; ++r)
            part[b * 4096 + (m * 16 + g * 4 + r) * 128 + nt * 16 + l15] += acc[m][nt][r];
    }
    __syncthreads();
  }
  {
    const int orow = tid >> 5;           // 0..31
    const int c0   = (tid & 31) * 4;
    f32x4 s = zero4;
#pragma unroll
    for (int b = 0; b < 8; ++b)
      s += *(const f32x4*)&part[b * 4096 + orow * 128 + c0];
    float zt = 0.f;
#pragma unroll
    for (int w2 = 0; w2 < 16; ++w2) zt += zred[w2][orow];
    *(f32x4*)&out[(size_t)(row0 + orow) * F_OUT + c0] = s * (1.0f / zt);
  }
}

// ---------------------------------------------------------------------------
// launch
// ---------------------------------------------------------------------------
extern "C" void kernel_launch(void* const* d_in, const int* in_sizes, int n_in,
                              void* d_out, int out_size, void* d_ws, size_t ws_size,
                              hipStream_t stream) {
  const float* H   = (const float*)d_in[0];   // [8192][768]
  const float* adj = (const float*)d_in[1];   // [8192][8192]
  const float* W   = (const float*)d_in[2];   // [768][128]
  const float* a   = (const float*)d_in[3];   // [256]
  float* out = (float*)d_out;                 // [8192][128]

  // workspace layout (~2.3 MB)
  char* ws = (char*)d_ws;
  f16_t* HpP  = (f16_t*)(ws);                  // 8192*128*2 = 2097152 (fragment-packed)
  f16_t* WT   = (f16_t*)(ws + 2097152);        // 128*768*2  = 196608
  float* wxs  = (float*)(ws + 2293760);        // 768*4
  float* wxd  = (float*)(ws + 2296832);        // 768*4
  float* srcv = (float*)(ws + 2299904);        // 8192*4
  float* dstv = (float*)(ws + 2332672);        // 8192*4

  prep      <<<dim3(288), dim3(256), 0, stream>>>(W, a, WT, wxs, wxd);
  hp_kernel <<<dim3(256), dim3(256), 0, stream>>>(H, WT, wxs, wxd, HpP, srcv, dstv);
  attn_kernel<<<dim3(256), dim3(1024), 0, stream>>>(adj, HpP, srcv, dstv, out);
}

// Round 6
// 401.174 us; speedup vs baseline: 1.2168x; 1.0247x over previous
//
#include <hip/hip_runtime.h>
#include <hip/hip_bf16.h>
#include <stdint.h>

// Problem constants
#define N_NODES 8192
#define F_IN    768
#define F_OUT   128

typedef _Float16 f16_t;
typedef _Float16 f16x8 __attribute__((ext_vector_type(8)));
typedef _Float16 f16x4 __attribute__((ext_vector_type(4)));
typedef float  f32x4  __attribute__((ext_vector_type(4)));
typedef unsigned short u16x4 __attribute__((ext_vector_type(4)));

static __device__ __forceinline__ unsigned short f16_bits(float x) {
  f16_t h = (f16_t)x;   // RTNE
  return __builtin_bit_cast(unsigned short, h);
}

static __device__ __forceinline__ void hard_barrier() {
  asm volatile("s_waitcnt lgkmcnt(0)" ::: "memory");
  __builtin_amdgcn_sched_barrier(0);
  __builtin_amdgcn_s_barrier();
  __builtin_amdgcn_sched_barrier(0);
}

// ---------------------------------------------------------------------------
// prep: blocks 0..95 -> WT[col][k] = f16(W[k][col]);
//       blocks 96..287 -> wxs/wxd[k] = sum_c W[k][c]*a[c] / a[128+c]
// ---------------------------------------------------------------------------
__global__ __launch_bounds__(256) void prep(const float* __restrict__ W,
                                            const float* __restrict__ a,
                                            f16_t* __restrict__ WT,
                                            float* __restrict__ wxs,
                                            float* __restrict__ wxd) {
  if (blockIdx.x < 96) {
    int gid = blockIdx.x * 256 + threadIdx.x;   // 24576 total
    int col = gid / 192;
    int kq  = gid % 192;
    int k0  = kq * 4;
    u16x4 u;
#pragma unroll
    for (int i = 0; i < 4; ++i)
      u[i] = f16_bits(W[(k0 + i) * F_OUT + col]);
    *(u16x4*)(WT + col * F_IN + k0) = u;
  } else {
    const int wave = threadIdx.x >> 6;
    const int lane = threadIdx.x & 63;
    const int row  = (blockIdx.x - 96) * 4 + wave;   // 0..767
    float w0 = W[row * F_OUT + lane];
    float w1 = W[row * F_OUT + 64 + lane];
    float s = w0 * a[lane]       + w1 * a[64 + lane];
    float d = w0 * a[128 + lane] + w1 * a[192 + lane];
#pragma unroll
    for (int m = 1; m <= 32; m <<= 1) {
      s += __shfl_xor(s, m);
      d += __shfl_xor(d, m);
    }
    if (lane == 0) { wxs[row] = s; wxd[row] = d; }
  }
}

// ---------------------------------------------------------------------------
// hp_kernel: Hp = H@W (f16 MFMA), written DIRECTLY in MFMA-B-fragment order:
//   fragment (j32, nt) = 512 f16 at ((j32*8+nt)*512); element (laneB, e)
//   holds Hp[j32*32 + (laneB>>4)*8 + e][nt*16 + (laneB&15)].
// src/dst = H @ wxs/wxd fused into the fp32 H loads (exact fp32).
// BM=32 rows/block, grid 256 x 256. RAW barriers (no vmcnt drain) +
// register prefetch of the next H chunk across the barriers.
// ---------------------------------------------------------------------------
__global__ __launch_bounds__(256, 2) void hp_kernel(
    const float* __restrict__ H, const f16_t* __restrict__ WT,
    const float* __restrict__ wxs, const float* __restrict__ wxd,
    f16_t* __restrict__ HpP, float* __restrict__ srcv, float* __restrict__ dstv)
{
  __shared__ unsigned short h_s[32 * 64];   // f16 H tile, swizzled
  __shared__ float ws_s[F_IN];
  __shared__ float wd_s[F_IN];

  const int tid  = threadIdx.x;
  const int wave = tid >> 6;
  const int lane = tid & 63;
  const int l15  = lane & 15;
  const int g    = lane >> 4;
  const int row0 = blockIdx.x * 32;
  const int lrow = tid >> 4;   // 0..15
  const int q    = tid & 15;

  for (int i = tid; i < F_IN; i += 256) { ws_s[i] = wxs[i]; wd_s[i] = wxd[i]; }

  f32x4 zero4 = {0.f, 0.f, 0.f, 0.f};
  f32x4 acc[2][2];
#pragma unroll
  for (int i = 0; i < 2; ++i)
#pragma unroll
    for (int j = 0; j < 2; ++j) acc[i][j] = zero4;
  float ps0 = 0.f, ps1 = 0.f, pd0 = 0.f, pd1 = 0.f;

  __syncthreads();

  // register prefetch of H chunks across raw barriers
  f32x4 h0 = *(const f32x4*)&H[(size_t)(row0 + lrow) * F_IN + q * 4];
  f32x4 h1 = *(const f32x4*)&H[(size_t)(row0 + 16 + lrow) * F_IN + q * 4];

  for (int c = 0; c < F_IN / 64; ++c) {
    const int k0 = c * 64;
    const int kn = (c < 11 ? c + 1 : 11) * 64;
    f32x4 h0n = *(const f32x4*)&H[(size_t)(row0 + lrow) * F_IN + kn + q * 4];
    f32x4 h1n = *(const f32x4*)&H[(size_t)(row0 + 16 + lrow) * F_IN + kn + q * 4];

    f32x4 as = *(const f32x4*)&ws_s[k0 + q * 4];
    f32x4 ad = *(const f32x4*)&wd_s[k0 + q * 4];
#pragma unroll
    for (int e = 0; e < 4; ++e) {
      ps0 += h0[e] * as[e]; pd0 += h0[e] * ad[e];
      ps1 += h1[e] * as[e]; pd1 += h1[e] * ad[e];
    }
    u16x4 u0, u1;
#pragma unroll
    for (int e = 0; e < 4; ++e) { u0[e] = f16_bits(h0[e]); u1[e] = f16_bits(h1[e]); }
    const int g8 = q >> 1, hh = (q & 1) * 4;
    *(u16x4*)&h_s[lrow * 64 + ((g8 ^ (lrow & 7)) * 8) + hh] = u0;
    const int r1 = lrow + 16;
    *(u16x4*)&h_s[r1 * 64 + ((g8 ^ (r1 & 7)) * 8) + hh] = u1;
    hard_barrier();

#pragma unroll
    for (int mt = 0; mt < 2; ++mt) {
      const int arow = mt * 16 + l15;
#pragma unroll
      for (int s = 0; s < 2; ++s) {
        f16x8 af = *(const f16x8*)&h_s[arow * 64 + (((s * 4 + g) ^ (arow & 7)) * 8)];
#pragma unroll
        for (int ntl = 0; ntl < 2; ++ntl) {
          const int nt = wave * 2 + ntl;
          f16x8 bfv = *(const f16x8*)&WT[(size_t)(nt * 16 + l15) * F_IN + k0 + s * 32 + g * 8];
          acc[mt][ntl] = __builtin_amdgcn_mfma_f32_16x16x32_f16(af, bfv, acc[mt][ntl], 0, 0, 0);
        }
      }
    }
    hard_barrier();
    h0 = h0n; h1 = h1n;
  }

  // exact fp32 src/dst: reduce over the 16 lanes sharing a row
#pragma unroll
  for (int m = 1; m <= 8; m <<= 1) {
    ps0 += __shfl_xor(ps0, m); ps1 += __shfl_xor(ps1, m);
    pd0 += __shfl_xor(pd0, m); pd1 += __shfl_xor(pd1, m);
  }
  if (q == 0) {
    srcv[row0 + lrow] = ps0; srcv[row0 + 16 + lrow] = ps1;
    dstv[row0 + lrow] = pd0; dstv[row0 + 16 + lrow] = pd1;
  }

  // Direct fragment-order store (coalesced).
  const int j32 = row0 >> 5;
#pragma unroll
  for (int mt = 0; mt < 2; ++mt)
#pragma unroll
    for (int ntl = 0; ntl < 2; ++ntl) {
      const int ntB = wave * 2 + ntl;
      const int gB  = mt * 2 + (g >> 1);
      f16x4 v;
#pragma unroll
      for (int r = 0; r < 4; ++r) v[r] = (f16_t)acc[mt][ntl][r];
      const size_t elem = ((size_t)(j32 * 8 + ntB)) * 512 + (gB * 16 + l15) * 8 + (g & 1) * 4;
      *(f16x4*)(HpP + elem) = v;
    }
}

// ---------------------------------------------------------------------------
// attn_kernel: out[i] = (sum_j w_ij * Hp[j]) / (sum_j w_ij)
//   w_ij = exp(lrelu(masked s_ij) - M_i), M_i = max(0, src_i + max_j dst_j)
// Grid 256 x 1024 thr. Block owns 32 rows; 32 steps of 256 j each.
// Per step: cooperative CONTIGUOUS adj tile load (nontemporal, reg-staged,
// 2-step prefetch) -> weights computed ONCE into swizzled LDS w_s (f16) ->
// raw barrier -> 16 waves (8 nt x 2 k-half) run 8 MFMAs each from w_s +
// packed Hp fragments (1KB contiguous, L2-hot) -> raw barrier.
// No __syncthreads (vmcnt-draining) in the loop; no global_load_lds.
// ---------------------------------------------------------------------------
__global__ __launch_bounds__(1024, 1) void attn_kernel(
    const float* __restrict__ adj, const f16_t* __restrict__ HpP,
    const float* __restrict__ srcv, const float* __restrict__ dstv,
    float* __restrict__ out)
{
  __shared__ __align__(16) float smem[8192];   // w_s (first 16KB) / partials (32KB)
  __shared__ float zred[32];
  __shared__ float mred[16];

  const int tid = threadIdx.x;
  const int wv  = tid >> 6;
  const int ln  = tid & 63;
  const int l15 = ln & 15;
  const int lg  = ln >> 4;
  const int row0 = blockIdx.x * 32;

  const int wr = tid >> 5;          // weight-phase row 0..31
  const int wc = (tid & 31) * 8;    // weight-phase col base (8 cols/thread)
  const int nt = wv & 7;            // MFMA job: output col tile
  const int kh = wv >> 3;           // MFMA job: k-half (4 of 8 k-tiles)

  unsigned short* w_s = (unsigned short*)smem;
  const int gstore = wr * 32 + ((wc >> 3) ^ (wr & 7));   // swizzled granule idx

  // prologue: global max(dst)
  float mloc = -3.0e38f;
#pragma unroll
  for (int i = 0; i < 2; ++i) {
    f32x4 v = ((const f32x4*)dstv)[i * 1024 + tid];
    mloc = fmaxf(mloc, fmaxf(fmaxf(v[0], v[1]), fmaxf(v[2], v[3])));
  }
#pragma unroll
  for (int m = 1; m <= 32; m <<= 1) mloc = fmaxf(mloc, __shfl_xor(mloc, m));
  if (ln == 0) mred[wv] = mloc;
  const float my_src = srcv[row0 + wr];
  __syncthreads();
  float maxdst = mred[0];
#pragma unroll
  for (int i = 1; i < 16; ++i) maxdst = fmaxf(maxdst, mred[i]);
  const float Mi = fmaxf(0.f, my_src + maxdst);
  const float wm = __expf(-Mi);     // masked entries: exp(0 - Mi)

  const float* adjr = adj + (size_t)(row0 + wr) * N_NODES + wc;

  f32x4 zero4 = {0.f, 0.f, 0.f, 0.f};
  f32x4 acc0 = zero4, acc1 = zero4;
  float z = 0.f;

  // 2-step register prefetch (adj nontemporal: keep L2 for HpP)
  f32x4 c0  = __builtin_nontemporal_load((const f32x4*)(adjr));
  f32x4 c1  = __builtin_nontemporal_load((const f32x4*)(adjr + 4));
  f32x4 cd0 = *(const f32x4*)(dstv + wc);
  f32x4 cd1 = *(const f32x4*)(dstv + wc + 4);
  f32x4 n0  = __builtin_nontemporal_load((const f32x4*)(adjr + 256));
  f32x4 n1  = __builtin_nontemporal_load((const f32x4*)(adjr + 260));
  f32x4 nd0 = *(const f32x4*)(dstv + 256 + wc);
  f32x4 nd1 = *(const f32x4*)(dstv + 256 + wc + 4);

  for (int s = 0; s < 32; ++s) {
    // Hp fragments for this step's wave job (issued early; consumed post-barrier)
    const f16_t* hb = HpP + (((size_t)s * 8 + kh * 4) * 8 + nt) * 512 + ln * 8;
    f16x8 bf0 = *(const f16x8*)(hb);
    f16x8 bf1 = *(const f16x8*)(hb + 4096);
    f16x8 bf2 = *(const f16x8*)(hb + 8192);
    f16x8 bf3 = *(const f16x8*)(hb + 12288);

    // weights for 8 columns of this thread's row
    f16x8 wq;
#pragma unroll
    for (int e = 0; e < 4; ++e) {
      float sc = my_src + cd0[e];
      float lr = fmaxf(sc, 0.2f * sc);
      float w  = (c0[e] != 0.f) ? __expf(lr - Mi) : wm;
      f16_t qv = (f16_t)w;
      z += (float)qv;
      wq[e] = qv;
    }
#pragma unroll
    for (int e = 0; e < 4; ++e) {
      float sc = my_src + cd1[e];
      float lr = fmaxf(sc, 0.2f * sc);
      float w  = (c1[e] != 0.f) ? __expf(lr - Mi) : wm;
      f16_t qv = (f16_t)w;
      z += (float)qv;
      wq[4 + e] = qv;
    }

    // issue prefetch for step s+2 (after cur regs consumed)
    const int sp = (s < 30) ? s + 2 : 31;
    f32x4 m0  = __builtin_nontemporal_load((const f32x4*)(adjr + sp * 256));
    f32x4 m1  = __builtin_nontemporal_load((const f32x4*)(adjr + sp * 256 + 4));
    f32x4 md0 = *(const f32x4*)(dstv + sp * 256 + wc);
    f32x4 md1 = *(const f32x4*)(dstv + sp * 256 + wc + 4);

    *(f16x8*)&w_s[gstore * 8] = wq;
    hard_barrier();                       // w_s ready (lgkm only; loads stay in flight)

#pragma unroll
    for (int k4 = 0; k4 < 4; ++k4) {
      const int kk = kh * 4 + k4;
      const int R0 = l15, R1 = 16 + l15;
      f16x8 a0 = *(const f16x8*)&w_s[(R0 * 32 + ((kk * 4 + lg) ^ (R0 & 7))) * 8];
      f16x8 a1 = *(const f16x8*)&w_s[(R1 * 32 + ((kk * 4 + lg) ^ (R1 & 7))) * 8];
      f16x8 bb = (k4 == 0) ? bf0 : (k4 == 1) ? bf1 : (k4 == 2) ? bf2 : bf3;
      acc0 = __builtin_amdgcn_mfma_f32_16x16x32_f16(a0, bb, acc0, 0, 0, 0);
      acc1 = __builtin_amdgcn_mfma_f32_16x16x32_f16(a1, bb, acc1, 0, 0, 0);
    }
    hard_barrier();                       // w_s consumed

    c0 = n0; c1 = n1; cd0 = nd0; cd1 = nd1;
    n0 = m0; n1 = m1; nd0 = md0; nd1 = md1;
  }

  // z: sum over the 32 threads sharing a row
#pragma unroll
  for (int m = 1; m <= 16; m <<= 1) z += __shfl_xor(z, m);
  if ((tid & 31) == 0) zred[wr] = z;

  // partials: smem[kh][row32][col128]
#pragma unroll
  for (int r = 0; r < 4; ++r) {
    smem[kh * 4096 + (lg * 4 + r) * 128 + nt * 16 + l15]        = acc0[r];
    smem[kh * 4096 + (16 + lg * 4 + r) * 128 + nt * 16 + l15]   = acc1[r];
  }
  __syncthreads();
  {
    const int orow = tid >> 5;
    const int c0o  = (tid & 31) * 4;
    f32x4 p0 = *(const f32x4*)&smem[orow * 128 + c0o];
    f32x4 p1 = *(const f32x4*)&smem[4096 + orow * 128 + c0o];
    f32x4 res = (p0 + p1) * (1.0f / zred[orow]);
    *(f32x4*)&out[(size_t)(row0 + orow) * F_OUT + c0o] = res;
  }
}

// ---------------------------------------------------------------------------
// launch
// ---------------------------------------------------------------------------
extern "C" void kernel_launch(void* const* d_in, const int* in_sizes, int n_in,
                              void* d_out, int out_size, void* d_ws, size_t ws_size,
                              hipStream_t stream) {
  const float* H   = (const float*)d_in[0];   // [8192][768]
  const float* adj = (const float*)d_in[1];   // [8192][8192]
  const float* W   = (const float*)d_in[2];   // [768][128]
  const float* a   = (const float*)d_in[3];   // [256]
  float* out = (float*)d_out;                 // [8192][128]

  // workspace layout (~2.3 MB)
  char* ws = (char*)d_ws;
  f16_t* HpP  = (f16_t*)(ws);                  // 8192*128*2 = 2097152 (fragment-packed)
  f16_t* WT   = (f16_t*)(ws + 2097152);        // 128*768*2  = 196608
  float* wxs  = (float*)(ws + 2293760);        // 768*4
  float* wxd  = (float*)(ws + 2296832);        // 768*4
  float* srcv = (float*)(ws + 2299904);        // 8192*4
  float* dstv = (float*)(ws + 2332672);        // 8192*4

  prep      <<<dim3(288), dim3(256), 0, stream>>>(W, a, WT, wxs, wxd);
  hp_kernel <<<dim3(256), dim3(256), 0, stream>>>(H, WT, wxs, wxd, HpP, srcv, dstv);
  attn_kernel<<<dim3(256), dim3(1024), 0, stream>>>(adj, HpP, srcv, dstv, out);
}